// Round 20
// baseline (237.697 us; speedup 1.0000x reference)
//
#include <hip/hip_runtime.h>
#include <math.h>

#define N_USERS 100000
#define N_ITEMS 40000
#define N_NODES (N_USERS + N_ITEMS)
#define EMB 128
#define EMBQ (EMB / 4)            /* 32 uints of packed 4x fp8 per row */
#define EMBH (EMB / 2)            /* 64 uints of packed 2x bf16 per row */
#define BATCH 8192
#define N_EDGES 1000000
#define ALPHA 0.1f
#define GAMMA 0.01f
#define FP8_SCALE 32.0f
#define INV_FP8_SCALE (1.0f / FP8_SCALE)

/* ---- bucket-sort CSR build geometry ---- */
#define RB_U 512                                /* rows per user bucket (shift 9) */
#define NB_U ((N_USERS + RB_U - 1) / RB_U)      /* 196 */
#define RB_I 256                                /* rows per item bucket (shift 8) */
#define NB_I ((N_ITEMS + RB_I - 1) / RB_I)      /* 157 */
#define NB_T (NB_U + NB_I)                      /* 353 */
#define PART_BLOCKS 256

#define CSRU_MAX (N_EDGES + 4 * (NB_U * RB_U))  /* u16 entries */
#define CSRI_MAX (N_EDGES + 4 * (NB_I * RB_I))  /* u32 entries */

#define UBLK8 ((N_USERS + 7) / 8)               /* 12500: 8 rows per block */
#define IBLK8 ((N_ITEMS + 7) / 8)               /* 5000 */

#define LOSS_BLOCKS 1024

typedef float f32x2 __attribute__((ext_vector_type(2)));

// ---------- bf16 pack/unpack (RNE) -------------------------------------------
__device__ inline unsigned int f2bf(float x) {
    const unsigned int b = __float_as_uint(x);
    return (b + 0x7FFFu + ((b >> 16) & 1u)) >> 16;
}
__device__ inline float bfl(unsigned int w) { return __uint_as_float(w << 16); }
__device__ inline float bfh(unsigned int w) { return __uint_as_float(w & 0xFFFF0000u); }

// ---------- fp8x4 dot-accumulate helper --------------------------------------
__device__ inline void acc4(unsigned int v, float& s0, float& s1, float& s2, float& s3) {
    const f32x2 lo = __builtin_amdgcn_cvt_pk_f32_fp8((int)v, false);
    const f32x2 hi = __builtin_amdgcn_cvt_pk_f32_fp8((int)v, true);
    s0 += lo.x; s1 += lo.y; s2 += hi.x; s3 += hi.y;
}

// ============ CSR build (bucket sort + ticket allocation, no scans) ===========
// tickets: tk[0]=part_u, tk[1]=part_i, tk[2]=csr_u, tk[3]=csr_i, tk[4]=loss done

// ---- A: per-block bucket histograms; block 0 zeroes sums + tickets -----------
__global__ void bucketA(const int* __restrict__ eu, const int* __restrict__ ev,
                        int* __restrict__ histA /* [PART_BLOCKS][NB_T] */,
                        float* __restrict__ sums, int* __restrict__ tk) {
    if (blockIdx.x == 0 && threadIdx.x < 16) {
        if (threadIdx.x < 4) sums[threadIdx.x] = 0.f;
        else if (threadIdx.x < 9) tk[threadIdx.x - 4] = 0;
    }
    __shared__ int h[NB_T];
    for (int k = threadIdx.x; k < NB_T; k += 256) h[k] = 0;
    __syncthreads();
    const int b = blockIdx.x;
    const int beg = (int)((long long)N_EDGES * b / PART_BLOCKS);
    const int end = (int)((long long)N_EDGES * (b + 1) / PART_BLOCKS);
    for (int i = beg + threadIdx.x; i < end; i += 256) {
        const int u = __builtin_nontemporal_load(&eu[i]);
        const int v = __builtin_nontemporal_load(&ev[i]);
        atomicAdd(&h[u >> 9], 1);
        atomicAdd(&h[NB_U + (v >> 8)], 1);
    }
    __syncthreads();
    for (int k = threadIdx.x; k < NB_T; k += 256) histA[b * NB_T + k] = h[k];
}

// ---- B1: per-bucket scan over block counts + TICKET part-region claim --------
__global__ void bucketB1(const int* __restrict__ histA, int* __restrict__ woff,
                         int* __restrict__ bktCnt, int* __restrict__ bktBase,
                         int* __restrict__ tk) {
    const int k = blockIdx.x;            // bucket id
    const int t = threadIdx.x;           // block id b = t (256 threads)
    const int lane = t & 63, wid = t >> 6;
    const int v = histA[t * NB_T + k];
    int x = v;
    #pragma unroll
    for (int off = 1; off < 64; off <<= 1) {
        const int y = __shfl_up(x, off);
        if (lane >= off) x += y;
    }
    __shared__ int wt[4];
    __shared__ int base;
    if (lane == 63) wt[wid] = x;
    __syncthreads();
    int wo = 0;
    for (int q = 0; q < wid; ++q) wo += wt[q];
    if (t == 255) {
        const int tot = wo + x;
        bktCnt[k] = tot;
        const int b0 = atomicAdd(&tk[(k < NB_U) ? 0 : 1], tot);  // claim region
        base = b0;
        bktBase[k] = b0;
    }
    __syncthreads();
    woff[t * NB_T + k] = base + wo + x - v;   // absolute exclusive offset
}

// ---- C: partition edges into bucket-contiguous arrays (packed u32) -----------
// pack user-part:  lrow(9b) | v<<9   pack item-part:  lrow(8b) | u<<8
__global__ void bucketC(const int* __restrict__ eu, const int* __restrict__ ev,
                        const int* __restrict__ woff,
                        unsigned int* __restrict__ part_u,
                        unsigned int* __restrict__ part_i) {
    __shared__ int cur[NB_T];
    const int b = blockIdx.x;
    for (int k = threadIdx.x; k < NB_T; k += 256)
        cur[k] = woff[b * NB_T + k];
    __syncthreads();
    const int beg = (int)((long long)N_EDGES * b / PART_BLOCKS);
    const int end = (int)((long long)N_EDGES * (b + 1) / PART_BLOCKS);
    for (int i = beg + threadIdx.x; i < end; i += 256) {
        const int u = __builtin_nontemporal_load(&eu[i]);
        const int v = __builtin_nontemporal_load(&ev[i]);
        const int pu = atomicAdd(&cur[u >> 9], 1);
        part_u[pu] = (unsigned int)((u & (RB_U - 1)) | (v << 9));
        const int pi = atomicAdd(&cur[NB_U + (v >> 8)], 1);
        part_i[pi] = (unsigned int)((v & (RB_I - 1)) | (u << 8));
    }
}

// ---- csr_build: histogram + prefix + TICKET csr claim + pad + rank-scatter ---
__global__ void csr_build(const unsigned int* __restrict__ part_u,
                          const unsigned int* __restrict__ part_i,
                          const int* __restrict__ bktBase, const int* __restrict__ bktCnt,
                          int* __restrict__ tk,
                          int* __restrict__ deg, float* __restrict__ isq_u,
                          float* __restrict__ isq_i,
                          int* __restrict__ rs_u, int* __restrict__ rs_i,
                          int* __restrict__ rend_u, int* __restrict__ rend_i,
                          unsigned short* __restrict__ csr_u, int* __restrict__ csr_i) {
    const int k = blockIdx.x;
    const bool isU = (k < NB_U);
    const int R = isU ? RB_U : RB_I;
    const int row0 = isU ? k * RB_U : (k - NB_U) * RB_I;
    const int Nside = isU ? N_USERS : N_ITEMS;
    const unsigned int* part = isU ? part_u : part_i;
    const int mask = R - 1;
    const int shift = isU ? 9 : 8;
    __shared__ int dh[RB_U];
    __shared__ int cur[RB_U];
    __shared__ int cbase;
    for (int r = threadIdx.x; r < R; r += 256) dh[r] = 0;
    __syncthreads();
    const int base = bktBase[k], cnt = bktCnt[k];
    for (int j = threadIdx.x; j < cnt; j += 256)
        atomicAdd(&dh[part[base + j] & mask], 1);
    __syncthreads();
    const int t = threadIdx.x, lane = t & 63, wid = t >> 6;
    const int r0 = 2 * t, r1 = 2 * t + 1;
    const int d0 = (r0 < R) ? dh[r0] : 0;
    const int d1 = (r1 < R) ? dh[r1] : 0;
    const int v0 = (d0 + 3) & ~3, v1 = (d1 + 3) & ~3;   // pad to 4
    const int s = v0 + v1;
    int x = s;
    #pragma unroll
    for (int off = 1; off < 64; off <<= 1) {
        const int y = __shfl_up(x, off);
        if (lane >= off) x += y;
    }
    __shared__ int wtot[4];
    if (lane == 63) wtot[wid] = x;
    __syncthreads();
    int wo = 0;
    for (int q = 0; q < wid; ++q) wo += wtot[q];
    const int pref = wo + x - s;              // exclusive padded prefix in block
    if (t == 255) {
        cbase = atomicAdd(&tk[isU ? 2 : 3], wo + x);   // claim csr region
    }
    __syncthreads();
    const int cb = cbase;
    if (r0 < R && row0 + r0 < Nside) {
        const int st = cb + pref;
        deg[(isU ? 0 : N_USERS) + row0 + r0] = d0;
        cur[r0] = st;
        if (isU) { isq_u[row0 + r0] = (d0 > 0) ? (1.0f / sqrtf((float)d0)) : 0.f;
                   rs_u[row0 + r0] = st; rend_u[row0 + r0] = st + v0;
                   for (int q = d0; q < v0; ++q) csr_u[st + q] = (unsigned short)N_ITEMS; }
        else     { isq_i[row0 + r0] = (d0 > 0) ? (1.0f / sqrtf((float)d0)) : 0.f;
                   rs_i[row0 + r0] = st; rend_i[row0 + r0] = st + v0;
                   for (int q = d0; q < v0; ++q) csr_i[st + q] = N_USERS; }
    } else if (r0 < R) cur[r0] = 0;
    if (r1 < R && row0 + r1 < Nside) {
        const int st = cb + pref + v0;
        deg[(isU ? 0 : N_USERS) + row0 + r1] = d1;
        cur[r1] = st;
        if (isU) { isq_u[row0 + r1] = (d1 > 0) ? (1.0f / sqrtf((float)d1)) : 0.f;
                   rs_u[row0 + r1] = st; rend_u[row0 + r1] = st + v1;
                   for (int q = d1; q < v1; ++q) csr_u[st + q] = (unsigned short)N_ITEMS; }
        else     { isq_i[row0 + r1] = (d1 > 0) ? (1.0f / sqrtf((float)d1)) : 0.f;
                   rs_i[row0 + r1] = st; rend_i[row0 + r1] = st + v1;
                   for (int q = d1; q < v1; ++q) csr_i[st + q] = N_USERS; }
    } else if (r1 < R) cur[r1] = 0;
    __syncthreads();
    for (int j = threadIdx.x; j < cnt; j += 256) {
        const unsigned int e = part[base + j];
        const int pos = atomicAdd(&cur[e & mask], 1);
        const int col = (int)(e >> shift);
        if (isU) csr_u[pos] = (unsigned short)col; else csr_i[pos] = col;
    }
}

// ================== embedding pipeline ========================================

// -------- init: e0{u,i} = fp8(S*isq*x0); x0b = bf16(x0); +zero dummy rows -----
__global__ void init_kernel(const float* __restrict__ user_emb,
                            const float* __restrict__ item_emb,
                            const float* __restrict__ isq_u,
                            const float* __restrict__ isq_i,
                            unsigned int* __restrict__ e0u,
                            unsigned int* __restrict__ e0i,
                            unsigned int* __restrict__ e1u,
                            unsigned int* __restrict__ e2u,
                            unsigned int* __restrict__ e3u,
                            unsigned int* __restrict__ e1i,
                            unsigned int* __restrict__ e2i,
                            unsigned int* __restrict__ e3i,
                            unsigned int* __restrict__ x0b) {
    if (blockIdx.x == 0 && threadIdx.x < 256) {
        const int t = threadIdx.x;   // 8 buffers x 32 words
        unsigned int* bufs[8] = {e0u, e1u, e2u, e3u, e0i, e1i, e2i, e3i};
        const int b = t >> 5;
        const size_t row = (b < 4) ? (size_t)N_USERS : (size_t)N_ITEMS;
        bufs[b][row * EMBQ + (t & 31)] = 0u;
    }
    const int total = N_NODES * EMBQ;
    const int utotal = N_USERS * EMBQ;
    int i = blockIdx.x * blockDim.x + threadIdx.x;
    const int stride = gridDim.x * blockDim.x;
    for (; i < total; i += stride) {
        const int node = i >> 5;
        const int q    = i & 31;
        float4 v; float n;
        if (node < N_USERS) {
            v = ((const float4*)(user_emb + (size_t)node * EMB))[q];
            n = FP8_SCALE * isq_u[node];
        } else {
            v = ((const float4*)(item_emb + (size_t)(node - N_USERS) * EMB))[q];
            n = FP8_SCALE * isq_i[node - N_USERS];
        }
        int pk = __builtin_amdgcn_cvt_pk_fp8_f32(n * v.x, n * v.y, 0, false);
        pk = __builtin_amdgcn_cvt_pk_fp8_f32(n * v.z, n * v.w, pk, true);
        if (node < N_USERS) e0u[i] = (unsigned int)pk;
        else                e0i[i - utotal] = (unsigned int)pk;
        const size_t xb = (size_t)node * EMBH + q * 2;
        x0b[xb]     = f2bf(v.x) | (f2bf(v.y) << 16);
        x0b[xb + 1] = f2bf(v.z) | (f2bf(v.w) << 16);
    }
}

// ---- fused per-layer SpMM: ITEM blocks first (long pole), then user blocks ---
__global__ void spmm_fused(const unsigned int* __restrict__ cur_u,
                           const unsigned int* __restrict__ cur_i,
                           unsigned int* __restrict__ nxt_u,
                           unsigned int* __restrict__ nxt_i,
                           const int* __restrict__ rs_u,
                           const int* __restrict__ rs_i,
                           const int* __restrict__ rend_u,
                           const int* __restrict__ rend_i,
                           const unsigned short* __restrict__ csr_u,
                           const int* __restrict__ csr_i,
                           const float* __restrict__ isq_u,
                           const float* __restrict__ isq_i) {
    const int lane = threadIdx.x & 63;
    const int half = lane >> 5;
    const int sub  = lane & 31;
    const int b = blockIdx.x;
    const int hw = (threadIdx.x >> 6) * 2 + half;    // half-wave id 0..7
    float s0 = 0.f, s1 = 0.f, s2 = 0.f, s3 = 0.f;
    if (b < IBLK8) {                                 // ---- item rows ----
        const int w = b * 8 + hw;
        if (w >= N_ITEMS) return;
        const int beg = rs_i[w];
        const int end = rend_i[w];
        int j = beg;
        for (; j + 8 <= end; j += 8) {
            const int4 ca = *(const int4*)(csr_i + j);
            const int4 cb = *(const int4*)(csr_i + j + 4);
            const unsigned int v0 = cur_u[(size_t)ca.x * EMBQ + sub];
            const unsigned int v1 = cur_u[(size_t)ca.y * EMBQ + sub];
            const unsigned int v2 = cur_u[(size_t)ca.z * EMBQ + sub];
            const unsigned int v3 = cur_u[(size_t)ca.w * EMBQ + sub];
            const unsigned int v4 = cur_u[(size_t)cb.x * EMBQ + sub];
            const unsigned int v5 = cur_u[(size_t)cb.y * EMBQ + sub];
            const unsigned int v6 = cur_u[(size_t)cb.z * EMBQ + sub];
            const unsigned int v7 = cur_u[(size_t)cb.w * EMBQ + sub];
            acc4(v0, s0, s1, s2, s3); acc4(v1, s0, s1, s2, s3);
            acc4(v2, s0, s1, s2, s3); acc4(v3, s0, s1, s2, s3);
            acc4(v4, s0, s1, s2, s3); acc4(v5, s0, s1, s2, s3);
            acc4(v6, s0, s1, s2, s3); acc4(v7, s0, s1, s2, s3);
        }
        if (j < end) {
            const int4 cc = *(const int4*)(csr_i + j);
            const unsigned int v0 = cur_u[(size_t)cc.x * EMBQ + sub];
            const unsigned int v1 = cur_u[(size_t)cc.y * EMBQ + sub];
            const unsigned int v2 = cur_u[(size_t)cc.z * EMBQ + sub];
            const unsigned int v3 = cur_u[(size_t)cc.w * EMBQ + sub];
            acc4(v0, s0, s1, s2, s3); acc4(v1, s0, s1, s2, s3);
            acc4(v2, s0, s1, s2, s3); acc4(v3, s0, s1, s2, s3);
        }
        const float n = isq_i[w];
        const float sc = n * n;
        int pk = __builtin_amdgcn_cvt_pk_fp8_f32(sc * s0, sc * s1, 0, false);
        pk = __builtin_amdgcn_cvt_pk_fp8_f32(sc * s2, sc * s3, pk, true);
        nxt_i[(size_t)w * EMBQ + sub] = (unsigned int)pk;
    } else {                                         // ---- user rows ----
        const int w = (b - IBLK8) * 8 + hw;
        if (w >= N_USERS) return;
        const int beg = rs_u[w];
        const int end = rend_u[w];
        int j = beg;
        for (; j + 8 <= end; j += 8) {
            const ushort4 ca = *(const ushort4*)(csr_u + j);
            const ushort4 cb = *(const ushort4*)(csr_u + j + 4);
            const unsigned int v0 = cur_i[(size_t)ca.x * EMBQ + sub];
            const unsigned int v1 = cur_i[(size_t)ca.y * EMBQ + sub];
            const unsigned int v2 = cur_i[(size_t)ca.z * EMBQ + sub];
            const unsigned int v3 = cur_i[(size_t)ca.w * EMBQ + sub];
            const unsigned int v4 = cur_i[(size_t)cb.x * EMBQ + sub];
            const unsigned int v5 = cur_i[(size_t)cb.y * EMBQ + sub];
            const unsigned int v6 = cur_i[(size_t)cb.z * EMBQ + sub];
            const unsigned int v7 = cur_i[(size_t)cb.w * EMBQ + sub];
            acc4(v0, s0, s1, s2, s3); acc4(v1, s0, s1, s2, s3);
            acc4(v2, s0, s1, s2, s3); acc4(v3, s0, s1, s2, s3);
            acc4(v4, s0, s1, s2, s3); acc4(v5, s0, s1, s2, s3);
            acc4(v6, s0, s1, s2, s3); acc4(v7, s0, s1, s2, s3);
        }
        if (j < end) {
            const ushort4 cc = *(const ushort4*)(csr_u + j);
            const unsigned int v0 = cur_i[(size_t)cc.x * EMBQ + sub];
            const unsigned int v1 = cur_i[(size_t)cc.y * EMBQ + sub];
            const unsigned int v2 = cur_i[(size_t)cc.z * EMBQ + sub];
            const unsigned int v3 = cur_i[(size_t)cc.w * EMBQ + sub];
            acc4(v0, s0, s1, s2, s3); acc4(v1, s0, s1, s2, s3);
            acc4(v2, s0, s1, s2, s3); acc4(v3, s0, s1, s2, s3);
        }
        const float n = isq_u[w];
        const float sc = n * n;
        int pk = __builtin_amdgcn_cvt_pk_fp8_f32(sc * s0, sc * s1, 0, false);
        pk = __builtin_amdgcn_cvt_pk_fp8_f32(sc * s2, sc * s3, pk, true);
        nxt_u[(size_t)w * EMBQ + sub] = (unsigned int)pk;
    }
}

__device__ inline float logsigmoidf(float x) {
    return (x >= 0.f) ? -log1pf(expf(-x)) : (x - log1pf(expf(x)));
}

// ---------------- fused losses + finalize (completion-counter) ----------------
__global__ void loss_kernel(const unsigned int* __restrict__ x0b,
                            const unsigned short* __restrict__ e1u,
                            const unsigned short* __restrict__ e2u,
                            const unsigned short* __restrict__ e3u,
                            const unsigned short* __restrict__ e1i,
                            const unsigned short* __restrict__ e2i,
                            const unsigned short* __restrict__ e3i,
                            const int* __restrict__ deg,
                            const int* __restrict__ users,
                            const int* __restrict__ pos_items,
                            const int* __restrict__ neg_items,
                            const int* __restrict__ sampled_user,
                            const int* __restrict__ sampled_items,
                            float* __restrict__ sums,
                            int* __restrict__ done,
                            float* __restrict__ out) {
    const int lane = threadIdx.x & 63;
    const int wid  = threadIdx.x >> 6;
    const int gw   = blockIdx.x * 4 + wid;
    const int nw   = gridDim.x * 4;
    float s_bce = 0.f, s_pred = 0.f, s_plogp = 0.f, s_ul = 0.f;
    for (int p = gw; p < 4 * BATCH; p += nw) {
        int u, it;
        if (p < 2 * BATCH) {
            if (p < BATCH) { u = users[p];          it = pos_items[p]; }
            else           { u = users[p - BATCH];  it = neg_items[p - BATCH]; }
        } else {
            const int q = p - 2 * BATCH;
            u = sampled_user[q]; it = sampled_items[q];
        }
        const float sdu = sqrtf((float)deg[u]) * INV_FP8_SCALE;
        const unsigned int a0 = x0b[(size_t)u * EMBH + lane];
        const size_t ui = (size_t)u * 64 + lane;
        const f32x2 u1 = __builtin_amdgcn_cvt_pk_f32_fp8((int)e1u[ui], false);
        const f32x2 u2 = __builtin_amdgcn_cvt_pk_f32_fp8((int)e2u[ui], false);
        const f32x2 u3 = __builtin_amdgcn_cvt_pk_f32_fp8((int)e3u[ui], false);
        const float ax = bfl(a0) + sdu * (u1.x + u2.x + u3.x);
        const float ay = bfh(a0) + sdu * (u1.y + u2.y + u3.y);
        const float sdi = sqrtf((float)deg[N_USERS + it]) * INV_FP8_SCALE;
        const unsigned int b0 = x0b[(size_t)(N_USERS + it) * EMBH + lane];
        const size_t ii = (size_t)it * 64 + lane;
        const f32x2 i1 = __builtin_amdgcn_cvt_pk_f32_fp8((int)e1i[ii], false);
        const f32x2 i2 = __builtin_amdgcn_cvt_pk_f32_fp8((int)e2i[ii], false);
        const f32x2 i3 = __builtin_amdgcn_cvt_pk_f32_fp8((int)e3i[ii], false);
        const float bx = bfl(b0) + sdi * (i1.x + i2.x + i3.x);
        const float by = bfh(b0) + sdi * (i1.y + i2.y + i3.y);
        float d = ax * bx + ay * by;
        #pragma unroll
        for (int off = 32; off > 0; off >>= 1) d += __shfl_down(d, off);
        if (lane == 0) {
            d *= (1.f / 16.f);
            const float pred = 1.f / (1.f + expf(-d));
            if (p < 2 * BATCH) {
                const float ls  = logsigmoidf(d);
                const float lsn = logsigmoidf(-d);
                s_bce   += (p < BATCH) ? -ls : -lsn;
                s_pred  += pred;
                s_plogp += pred * ls;
            } else {
                s_ul += pred;
            }
        }
    }
    __shared__ float red[4][4];
    if (lane == 0) {
        red[wid][0] = s_bce; red[wid][1] = s_pred;
        red[wid][2] = s_plogp; red[wid][3] = s_ul;
    }
    __syncthreads();
    if (threadIdx.x < 4) {
        const float v = red[0][threadIdx.x] + red[1][threadIdx.x]
                      + red[2][threadIdx.x] + red[3][threadIdx.x];
        atomicAdd(&sums[threadIdx.x], v);
    }
    // fused finalize: last block to finish computes the outputs
    __syncthreads();
    __shared__ int last;
    if (threadIdx.x == 0) {
        __threadfence();
        last = (atomicAdd(done, 1) == (int)gridDim.x - 1);
    }
    __syncthreads();
    if (last && threadIdx.x == 0) {
        const float n = 2.f * BATCH;
        const float bce        = sums[0] / n;
        const float pred_avg   = sums[1] / n;
        const float plogp_avg  = sums[2] / n;
        const float predul_avg = sums[3] / n;
        const float info = ALPHA * (-pred_avg * logf(predul_avg)
                                    - (1.f - pred_avg) * logf(1.f - predul_avg))
                         + GAMMA * plogp_avg;
        out[0] = bce;
        out[1] = info;
    }
}

extern "C" void kernel_launch(void* const* d_in, const int* in_sizes, int n_in,
                              void* d_out, int out_size, void* d_ws, size_t ws_size,
                              hipStream_t stream) {
    const float* user_emb      = (const float*)d_in[0];
    const float* item_emb      = (const float*)d_in[1];
    const int*   edge_user     = (const int*)d_in[3];
    const int*   edge_item     = (const int*)d_in[4];
    const int*   users         = (const int*)d_in[5];
    const int*   pos_items     = (const int*)d_in[6];
    const int*   neg_items     = (const int*)d_in[7];
    const int*   sampled_user  = (const int*)d_in[8];
    const int*   sampled_items = (const int*)d_in[9];
    float* out = (float*)d_out;

    const size_t ebu = (size_t)(N_USERS + 1) * EMBQ * sizeof(unsigned int); // 12.8 MB
    const size_t ebi = (size_t)(N_ITEMS + 1) * EMBQ * sizeof(unsigned int); //  5.1 MB
    char* ws = (char*)d_ws;
    size_t off = 0;
    unsigned int* e0u = (unsigned int*)(ws + off); off += ebu;
    unsigned int* e1u = (unsigned int*)(ws + off); off += ebu;
    unsigned int* e2u = (unsigned int*)(ws + off); off += ebu;
    unsigned int* e3u = (unsigned int*)(ws + off); off += ebu;
    unsigned int* e0i = (unsigned int*)(ws + off); off += ebi;
    unsigned int* e1i = (unsigned int*)(ws + off); off += ebi;
    unsigned int* e2i = (unsigned int*)(ws + off); off += ebi;
    unsigned int* e3i = (unsigned int*)(ws + off); off += ebi;
    unsigned int* x0b = (unsigned int*)(ws + off); off += (size_t)N_NODES * EMBH * 4;
    float* sums = (float*)(ws + off); off += 256;
    int*   tk    = (int*)(ws + off); off += 256;     // tk[4] = loss completion
    int*   deg   = (int*)(ws + off); off += (size_t)N_NODES * 4;
    int*   rs_u  = (int*)(ws + off); off += (size_t)N_USERS * 4;
    int*   rs_i  = (int*)(ws + off); off += (size_t)N_ITEMS * 4;
    int*   rend_u = (int*)(ws + off); off += (size_t)N_USERS * 4;
    int*   rend_i = (int*)(ws + off); off += (size_t)N_ITEMS * 4;
    float* isq_u = (float*)(ws + off); off += (size_t)N_USERS * 4;
    float* isq_i = (float*)(ws + off); off += (size_t)N_ITEMS * 4;
    unsigned short* csr_u = (unsigned short*)(ws + off); off += (size_t)CSRU_MAX * 2 + 256;
    int*   csr_i = (int*)(ws + off); off += (size_t)CSRI_MAX * 4;
    unsigned int* part_u = (unsigned int*)(ws + off); off += (size_t)N_EDGES * 4;
    unsigned int* part_i = (unsigned int*)(ws + off); off += (size_t)N_EDGES * 4;
    int*   histA   = (int*)(ws + off); off += (size_t)PART_BLOCKS * NB_T * 4;
    int*   woff    = (int*)(ws + off); off += (size_t)PART_BLOCKS * NB_T * 4;
    int*   bktCnt  = (int*)(ws + off); off += (size_t)NB_T * 4;
    int*   bktBase = (int*)(ws + off); off += (size_t)NB_T * 4;

    bucketA<<<PART_BLOCKS, 256, 0, stream>>>(edge_user, edge_item, histA, sums, tk);
    bucketB1<<<NB_T, 256, 0, stream>>>(histA, woff, bktCnt, bktBase, tk);
    bucketC<<<PART_BLOCKS, 256, 0, stream>>>(edge_user, edge_item, woff,
                                             part_u, part_i);
    csr_build<<<NB_T, 256, 0, stream>>>(part_u, part_i, bktBase, bktCnt, tk,
                                        deg, isq_u, isq_i, rs_u, rs_i,
                                        rend_u, rend_i, csr_u, csr_i);
    init_kernel<<<4096, 256, 0, stream>>>(user_emb, item_emb, isq_u, isq_i,
                                          e0u, e0i, e1u, e2u, e3u, e1i, e2i, e3i,
                                          x0b);

    spmm_fused<<<UBLK8 + IBLK8, 256, 0, stream>>>(e0u, e0i, e1u, e1i, rs_u, rs_i,
                                                  rend_u, rend_i, csr_u, csr_i,
                                                  isq_u, isq_i);
    spmm_fused<<<UBLK8 + IBLK8, 256, 0, stream>>>(e1u, e1i, e2u, e2i, rs_u, rs_i,
                                                  rend_u, rend_i, csr_u, csr_i,
                                                  isq_u, isq_i);
    spmm_fused<<<UBLK8 + IBLK8, 256, 0, stream>>>(e2u, e2i, e3u, e3i, rs_u, rs_i,
                                                  rend_u, rend_i, csr_u, csr_i,
                                                  isq_u, isq_i);

    loss_kernel<<<LOSS_BLOCKS, 256, 0, stream>>>(x0b,
                                         (const unsigned short*)e1u,
                                         (const unsigned short*)e2u,
                                         (const unsigned short*)e3u,
                                         (const unsigned short*)e1i,
                                         (const unsigned short*)e2i,
                                         (const unsigned short*)e3i,
                                         deg, users, pos_items, neg_items,
                                         sampled_user, sampled_items, sums,
                                         &tk[4], out);
}

// Round 21
// 226.638 us; speedup vs baseline: 1.0488x; 1.0488x over previous
//
#include <hip/hip_runtime.h>
#include <math.h>

#define N_USERS 100000
#define N_ITEMS 40000
#define N_NODES (N_USERS + N_ITEMS)
#define EMB 128
#define EMBQ (EMB / 4)            /* 32 uints of packed 4x fp8 per row */
#define EMBH (EMB / 2)            /* 64 uints of packed 2x bf16 per row */
#define BATCH 8192
#define N_EDGES 1000000
#define ALPHA 0.1f
#define GAMMA 0.01f
#define FP8_SCALE 32.0f
#define INV_FP8_SCALE (1.0f / FP8_SCALE)

/* ---- bucket-sort CSR build geometry ---- */
#define RB_U 512                                /* rows per user bucket (shift 9) */
#define NB_U ((N_USERS + RB_U - 1) / RB_U)      /* 196 */
#define RB_I 256                                /* rows per item bucket (shift 8) */
#define NB_I ((N_ITEMS + RB_I - 1) / RB_I)      /* 157 */
#define NB_T (NB_U + NB_I)                      /* 353 */
#define PART_BLOCKS 256

#define CSRU_MAX (N_EDGES + 4 * (NB_U * RB_U))  /* u16 entries */
#define CSRI_MAX (N_EDGES + 4 * (NB_I * RB_I))  /* u32 entries */

#define UBLK8 ((N_USERS + 7) / 8)               /* 12500: 8 rows per block */
#define IBLK8 ((N_ITEMS + 7) / 8)               /* 5000 */

#define LOSS_BLOCKS 512

typedef float f32x2 __attribute__((ext_vector_type(2)));

// ---------- bf16 pack/unpack (RNE) -------------------------------------------
__device__ inline unsigned int f2bf(float x) {
    const unsigned int b = __float_as_uint(x);
    return (b + 0x7FFFu + ((b >> 16) & 1u)) >> 16;
}
__device__ inline float bfl(unsigned int w) { return __uint_as_float(w << 16); }
__device__ inline float bfh(unsigned int w) { return __uint_as_float(w & 0xFFFF0000u); }

// ---------- fp8x4 dot-accumulate helper --------------------------------------
__device__ inline void acc4(unsigned int v, float& s0, float& s1, float& s2, float& s3) {
    const f32x2 lo = __builtin_amdgcn_cvt_pk_f32_fp8((int)v, false);
    const f32x2 hi = __builtin_amdgcn_cvt_pk_f32_fp8((int)v, true);
    s0 += lo.x; s1 += lo.y; s2 += hi.x; s3 += hi.y;
}

// ============ CSR build (bucket sort + ticket allocation, no scans) ===========
// tickets: tk[0]=part_u, tk[1]=part_i, tk[2]=csr_u, tk[3]=csr_i

// ---- A: per-block bucket histograms; block 0 zeroes tickets -------------------
__global__ void bucketA(const int* __restrict__ eu, const int* __restrict__ ev,
                        int* __restrict__ histA /* [PART_BLOCKS][NB_T] */,
                        int* __restrict__ tk) {
    if (blockIdx.x == 0 && threadIdx.x < 4) tk[threadIdx.x] = 0;
    __shared__ int h[NB_T];
    for (int k = threadIdx.x; k < NB_T; k += 256) h[k] = 0;
    __syncthreads();
    const int b = blockIdx.x;
    const int beg = (int)((long long)N_EDGES * b / PART_BLOCKS);
    const int end = (int)((long long)N_EDGES * (b + 1) / PART_BLOCKS);
    for (int i = beg + threadIdx.x; i < end; i += 256) {
        const int u = __builtin_nontemporal_load(&eu[i]);
        const int v = __builtin_nontemporal_load(&ev[i]);
        atomicAdd(&h[u >> 9], 1);
        atomicAdd(&h[NB_U + (v >> 8)], 1);
    }
    __syncthreads();
    for (int k = threadIdx.x; k < NB_T; k += 256) histA[b * NB_T + k] = h[k];
}

// ---- B1: per-bucket scan over block counts + TICKET part-region claim --------
__global__ void bucketB1(const int* __restrict__ histA, int* __restrict__ woff,
                         int* __restrict__ bktCnt, int* __restrict__ bktBase,
                         int* __restrict__ tk) {
    const int k = blockIdx.x;            // bucket id
    const int t = threadIdx.x;           // block id b = t (256 threads)
    const int lane = t & 63, wid = t >> 6;
    const int v = histA[t * NB_T + k];
    int x = v;
    #pragma unroll
    for (int off = 1; off < 64; off <<= 1) {
        const int y = __shfl_up(x, off);
        if (lane >= off) x += y;
    }
    __shared__ int wt[4];
    __shared__ int base;
    if (lane == 63) wt[wid] = x;
    __syncthreads();
    int wo = 0;
    for (int q = 0; q < wid; ++q) wo += wt[q];
    if (t == 255) {
        const int tot = wo + x;
        bktCnt[k] = tot;
        const int b0 = atomicAdd(&tk[(k < NB_U) ? 0 : 1], tot);  // claim region
        base = b0;
        bktBase[k] = b0;
    }
    __syncthreads();
    woff[t * NB_T + k] = base + wo + x - v;   // absolute exclusive offset
}

// ---- C: partition edges into bucket-contiguous arrays (packed u32) -----------
// pack user-part:  lrow(9b) | v<<9   pack item-part:  lrow(8b) | u<<8
__global__ void bucketC(const int* __restrict__ eu, const int* __restrict__ ev,
                        const int* __restrict__ woff,
                        unsigned int* __restrict__ part_u,
                        unsigned int* __restrict__ part_i) {
    __shared__ int cur[NB_T];
    const int b = blockIdx.x;
    for (int k = threadIdx.x; k < NB_T; k += 256)
        cur[k] = woff[b * NB_T + k];
    __syncthreads();
    const int beg = (int)((long long)N_EDGES * b / PART_BLOCKS);
    const int end = (int)((long long)N_EDGES * (b + 1) / PART_BLOCKS);
    for (int i = beg + threadIdx.x; i < end; i += 256) {
        const int u = __builtin_nontemporal_load(&eu[i]);
        const int v = __builtin_nontemporal_load(&ev[i]);
        const int pu = atomicAdd(&cur[u >> 9], 1);
        part_u[pu] = (unsigned int)((u & (RB_U - 1)) | (v << 9));
        const int pi = atomicAdd(&cur[NB_U + (v >> 8)], 1);
        part_i[pi] = (unsigned int)((v & (RB_I - 1)) | (u << 8));
    }
}

// ---- csr_build: histogram + prefix + TICKET csr claim + pad + rank-scatter ---
__global__ void csr_build(const unsigned int* __restrict__ part_u,
                          const unsigned int* __restrict__ part_i,
                          const int* __restrict__ bktBase, const int* __restrict__ bktCnt,
                          int* __restrict__ tk,
                          int* __restrict__ deg, float* __restrict__ isq_u,
                          float* __restrict__ isq_i,
                          int* __restrict__ rs_u, int* __restrict__ rs_i,
                          int* __restrict__ rend_u, int* __restrict__ rend_i,
                          unsigned short* __restrict__ csr_u, int* __restrict__ csr_i) {
    const int k = blockIdx.x;
    const bool isU = (k < NB_U);
    const int R = isU ? RB_U : RB_I;
    const int row0 = isU ? k * RB_U : (k - NB_U) * RB_I;
    const int Nside = isU ? N_USERS : N_ITEMS;
    const unsigned int* part = isU ? part_u : part_i;
    const int mask = R - 1;
    const int shift = isU ? 9 : 8;
    __shared__ int dh[RB_U];
    __shared__ int cur[RB_U];
    __shared__ int cbase;
    for (int r = threadIdx.x; r < R; r += 256) dh[r] = 0;
    __syncthreads();
    const int base = bktBase[k], cnt = bktCnt[k];
    for (int j = threadIdx.x; j < cnt; j += 256)
        atomicAdd(&dh[part[base + j] & mask], 1);
    __syncthreads();
    const int t = threadIdx.x, lane = t & 63, wid = t >> 6;
    const int r0 = 2 * t, r1 = 2 * t + 1;
    const int d0 = (r0 < R) ? dh[r0] : 0;
    const int d1 = (r1 < R) ? dh[r1] : 0;
    const int v0 = (d0 + 3) & ~3, v1 = (d1 + 3) & ~3;   // pad to 4
    const int s = v0 + v1;
    int x = s;
    #pragma unroll
    for (int off = 1; off < 64; off <<= 1) {
        const int y = __shfl_up(x, off);
        if (lane >= off) x += y;
    }
    __shared__ int wtot[4];
    if (lane == 63) wtot[wid] = x;
    __syncthreads();
    int wo = 0;
    for (int q = 0; q < wid; ++q) wo += wtot[q];
    const int pref = wo + x - s;              // exclusive padded prefix in block
    if (t == 255) {
        cbase = atomicAdd(&tk[isU ? 2 : 3], wo + x);   // claim csr region
    }
    __syncthreads();
    const int cb = cbase;
    if (r0 < R && row0 + r0 < Nside) {
        const int st = cb + pref;
        deg[(isU ? 0 : N_USERS) + row0 + r0] = d0;
        cur[r0] = st;
        if (isU) { isq_u[row0 + r0] = (d0 > 0) ? (1.0f / sqrtf((float)d0)) : 0.f;
                   rs_u[row0 + r0] = st; rend_u[row0 + r0] = st + v0;
                   for (int q = d0; q < v0; ++q) csr_u[st + q] = (unsigned short)N_ITEMS; }
        else     { isq_i[row0 + r0] = (d0 > 0) ? (1.0f / sqrtf((float)d0)) : 0.f;
                   rs_i[row0 + r0] = st; rend_i[row0 + r0] = st + v0;
                   for (int q = d0; q < v0; ++q) csr_i[st + q] = N_USERS; }
    } else if (r0 < R) cur[r0] = 0;
    if (r1 < R && row0 + r1 < Nside) {
        const int st = cb + pref + v0;
        deg[(isU ? 0 : N_USERS) + row0 + r1] = d1;
        cur[r1] = st;
        if (isU) { isq_u[row0 + r1] = (d1 > 0) ? (1.0f / sqrtf((float)d1)) : 0.f;
                   rs_u[row0 + r1] = st; rend_u[row0 + r1] = st + v1;
                   for (int q = d1; q < v1; ++q) csr_u[st + q] = (unsigned short)N_ITEMS; }
        else     { isq_i[row0 + r1] = (d1 > 0) ? (1.0f / sqrtf((float)d1)) : 0.f;
                   rs_i[row0 + r1] = st; rend_i[row0 + r1] = st + v1;
                   for (int q = d1; q < v1; ++q) csr_i[st + q] = N_USERS; }
    } else if (r1 < R) cur[r1] = 0;
    __syncthreads();
    for (int j = threadIdx.x; j < cnt; j += 256) {
        const unsigned int e = part[base + j];
        const int pos = atomicAdd(&cur[e & mask], 1);
        const int col = (int)(e >> shift);
        if (isU) csr_u[pos] = (unsigned short)col; else csr_i[pos] = col;
    }
}

// ================== embedding pipeline ========================================

// -------- init: e0{u,i} = fp8(S*isq*x0); x0b = bf16(x0); +zero dummy rows -----
__global__ void init_kernel(const float* __restrict__ user_emb,
                            const float* __restrict__ item_emb,
                            const float* __restrict__ isq_u,
                            const float* __restrict__ isq_i,
                            unsigned int* __restrict__ e0u,
                            unsigned int* __restrict__ e0i,
                            unsigned int* __restrict__ e1u,
                            unsigned int* __restrict__ e2u,
                            unsigned int* __restrict__ e3u,
                            unsigned int* __restrict__ e1i,
                            unsigned int* __restrict__ e2i,
                            unsigned int* __restrict__ e3i,
                            unsigned int* __restrict__ x0b) {
    if (blockIdx.x == 0 && threadIdx.x < 256) {
        const int t = threadIdx.x;   // 8 buffers x 32 words
        unsigned int* bufs[8] = {e0u, e1u, e2u, e3u, e0i, e1i, e2i, e3i};
        const int b = t >> 5;
        const size_t row = (b < 4) ? (size_t)N_USERS : (size_t)N_ITEMS;
        bufs[b][row * EMBQ + (t & 31)] = 0u;
    }
    const int total = N_NODES * EMBQ;
    const int utotal = N_USERS * EMBQ;
    int i = blockIdx.x * blockDim.x + threadIdx.x;
    const int stride = gridDim.x * blockDim.x;
    for (; i < total; i += stride) {
        const int node = i >> 5;
        const int q    = i & 31;
        float4 v; float n;
        if (node < N_USERS) {
            v = ((const float4*)(user_emb + (size_t)node * EMB))[q];
            n = FP8_SCALE * isq_u[node];
        } else {
            v = ((const float4*)(item_emb + (size_t)(node - N_USERS) * EMB))[q];
            n = FP8_SCALE * isq_i[node - N_USERS];
        }
        int pk = __builtin_amdgcn_cvt_pk_fp8_f32(n * v.x, n * v.y, 0, false);
        pk = __builtin_amdgcn_cvt_pk_fp8_f32(n * v.z, n * v.w, pk, true);
        if (node < N_USERS) e0u[i] = (unsigned int)pk;
        else                e0i[i - utotal] = (unsigned int)pk;
        const size_t xb = (size_t)node * EMBH + q * 2;
        x0b[xb]     = f2bf(v.x) | (f2bf(v.y) << 16);
        x0b[xb + 1] = f2bf(v.z) | (f2bf(v.w) << 16);
    }
}

// ---- fused per-layer SpMM: ITEM blocks first (long pole), then user blocks ---
__global__ void spmm_fused(const unsigned int* __restrict__ cur_u,
                           const unsigned int* __restrict__ cur_i,
                           unsigned int* __restrict__ nxt_u,
                           unsigned int* __restrict__ nxt_i,
                           const int* __restrict__ rs_u,
                           const int* __restrict__ rs_i,
                           const int* __restrict__ rend_u,
                           const int* __restrict__ rend_i,
                           const unsigned short* __restrict__ csr_u,
                           const int* __restrict__ csr_i,
                           const float* __restrict__ isq_u,
                           const float* __restrict__ isq_i) {
    const int lane = threadIdx.x & 63;
    const int half = lane >> 5;
    const int sub  = lane & 31;
    const int b = blockIdx.x;
    const int hw = (threadIdx.x >> 6) * 2 + half;    // half-wave id 0..7
    float s0 = 0.f, s1 = 0.f, s2 = 0.f, s3 = 0.f;
    if (b < IBLK8) {                                 // ---- item rows ----
        const int w = b * 8 + hw;
        if (w >= N_ITEMS) return;
        const int beg = rs_i[w];
        const int end = rend_i[w];
        int j = beg;
        for (; j + 8 <= end; j += 8) {
            const int4 ca = *(const int4*)(csr_i + j);
            const int4 cb = *(const int4*)(csr_i + j + 4);
            const unsigned int v0 = cur_u[(size_t)ca.x * EMBQ + sub];
            const unsigned int v1 = cur_u[(size_t)ca.y * EMBQ + sub];
            const unsigned int v2 = cur_u[(size_t)ca.z * EMBQ + sub];
            const unsigned int v3 = cur_u[(size_t)ca.w * EMBQ + sub];
            const unsigned int v4 = cur_u[(size_t)cb.x * EMBQ + sub];
            const unsigned int v5 = cur_u[(size_t)cb.y * EMBQ + sub];
            const unsigned int v6 = cur_u[(size_t)cb.z * EMBQ + sub];
            const unsigned int v7 = cur_u[(size_t)cb.w * EMBQ + sub];
            acc4(v0, s0, s1, s2, s3); acc4(v1, s0, s1, s2, s3);
            acc4(v2, s0, s1, s2, s3); acc4(v3, s0, s1, s2, s3);
            acc4(v4, s0, s1, s2, s3); acc4(v5, s0, s1, s2, s3);
            acc4(v6, s0, s1, s2, s3); acc4(v7, s0, s1, s2, s3);
        }
        if (j < end) {
            const int4 cc = *(const int4*)(csr_i + j);
            const unsigned int v0 = cur_u[(size_t)cc.x * EMBQ + sub];
            const unsigned int v1 = cur_u[(size_t)cc.y * EMBQ + sub];
            const unsigned int v2 = cur_u[(size_t)cc.z * EMBQ + sub];
            const unsigned int v3 = cur_u[(size_t)cc.w * EMBQ + sub];
            acc4(v0, s0, s1, s2, s3); acc4(v1, s0, s1, s2, s3);
            acc4(v2, s0, s1, s2, s3); acc4(v3, s0, s1, s2, s3);
        }
        const float n = isq_i[w];
        const float sc = n * n;
        int pk = __builtin_amdgcn_cvt_pk_fp8_f32(sc * s0, sc * s1, 0, false);
        pk = __builtin_amdgcn_cvt_pk_fp8_f32(sc * s2, sc * s3, pk, true);
        nxt_i[(size_t)w * EMBQ + sub] = (unsigned int)pk;
    } else {                                         // ---- user rows ----
        const int w = (b - IBLK8) * 8 + hw;
        if (w >= N_USERS) return;
        const int beg = rs_u[w];
        const int end = rend_u[w];
        int j = beg;
        for (; j + 8 <= end; j += 8) {
            const ushort4 ca = *(const ushort4*)(csr_u + j);
            const ushort4 cb = *(const ushort4*)(csr_u + j + 4);
            const unsigned int v0 = cur_i[(size_t)ca.x * EMBQ + sub];
            const unsigned int v1 = cur_i[(size_t)ca.y * EMBQ + sub];
            const unsigned int v2 = cur_i[(size_t)ca.z * EMBQ + sub];
            const unsigned int v3 = cur_i[(size_t)ca.w * EMBQ + sub];
            const unsigned int v4 = cur_i[(size_t)cb.x * EMBQ + sub];
            const unsigned int v5 = cur_i[(size_t)cb.y * EMBQ + sub];
            const unsigned int v6 = cur_i[(size_t)cb.z * EMBQ + sub];
            const unsigned int v7 = cur_i[(size_t)cb.w * EMBQ + sub];
            acc4(v0, s0, s1, s2, s3); acc4(v1, s0, s1, s2, s3);
            acc4(v2, s0, s1, s2, s3); acc4(v3, s0, s1, s2, s3);
            acc4(v4, s0, s1, s2, s3); acc4(v5, s0, s1, s2, s3);
            acc4(v6, s0, s1, s2, s3); acc4(v7, s0, s1, s2, s3);
        }
        if (j < end) {
            const ushort4 cc = *(const ushort4*)(csr_u + j);
            const unsigned int v0 = cur_i[(size_t)cc.x * EMBQ + sub];
            const unsigned int v1 = cur_i[(size_t)cc.y * EMBQ + sub];
            const unsigned int v2 = cur_i[(size_t)cc.z * EMBQ + sub];
            const unsigned int v3 = cur_i[(size_t)cc.w * EMBQ + sub];
            acc4(v0, s0, s1, s2, s3); acc4(v1, s0, s1, s2, s3);
            acc4(v2, s0, s1, s2, s3); acc4(v3, s0, s1, s2, s3);
        }
        const float n = isq_u[w];
        const float sc = n * n;
        int pk = __builtin_amdgcn_cvt_pk_fp8_f32(sc * s0, sc * s1, 0, false);
        pk = __builtin_amdgcn_cvt_pk_fp8_f32(sc * s2, sc * s3, pk, true);
        nxt_u[(size_t)w * EMBQ + sub] = (unsigned int)pk;
    }
}

__device__ inline float logsigmoidf(float x) {
    return (x >= 0.f) ? -log1pf(expf(-x)) : (x - log1pf(expf(x)));
}

// ---------------- fused losses: per-block partials, NO atomics ----------------
__global__ void loss_kernel(const unsigned int* __restrict__ x0b,
                            const unsigned short* __restrict__ e1u,
                            const unsigned short* __restrict__ e2u,
                            const unsigned short* __restrict__ e3u,
                            const unsigned short* __restrict__ e1i,
                            const unsigned short* __restrict__ e2i,
                            const unsigned short* __restrict__ e3i,
                            const int* __restrict__ deg,
                            const int* __restrict__ users,
                            const int* __restrict__ pos_items,
                            const int* __restrict__ neg_items,
                            const int* __restrict__ sampled_user,
                            const int* __restrict__ sampled_items,
                            float* __restrict__ lossPart) {
    const int lane = threadIdx.x & 63;
    const int wid  = threadIdx.x >> 6;
    const int gw   = blockIdx.x * 4 + wid;
    const int nw   = gridDim.x * 4;
    float s_bce = 0.f, s_pred = 0.f, s_plogp = 0.f, s_ul = 0.f;
    for (int p = gw; p < 4 * BATCH; p += nw) {
        int u, it;
        if (p < 2 * BATCH) {
            if (p < BATCH) { u = users[p];          it = pos_items[p]; }
            else           { u = users[p - BATCH];  it = neg_items[p - BATCH]; }
        } else {
            const int q = p - 2 * BATCH;
            u = sampled_user[q]; it = sampled_items[q];
        }
        const float sdu = sqrtf((float)deg[u]) * INV_FP8_SCALE;
        const unsigned int a0 = x0b[(size_t)u * EMBH + lane];
        const size_t ui = (size_t)u * 64 + lane;
        const f32x2 u1 = __builtin_amdgcn_cvt_pk_f32_fp8((int)e1u[ui], false);
        const f32x2 u2 = __builtin_amdgcn_cvt_pk_f32_fp8((int)e2u[ui], false);
        const f32x2 u3 = __builtin_amdgcn_cvt_pk_f32_fp8((int)e3u[ui], false);
        const float ax = bfl(a0) + sdu * (u1.x + u2.x + u3.x);
        const float ay = bfh(a0) + sdu * (u1.y + u2.y + u3.y);
        const float sdi = sqrtf((float)deg[N_USERS + it]) * INV_FP8_SCALE;
        const unsigned int b0 = x0b[(size_t)(N_USERS + it) * EMBH + lane];
        const size_t ii = (size_t)it * 64 + lane;
        const f32x2 i1 = __builtin_amdgcn_cvt_pk_f32_fp8((int)e1i[ii], false);
        const f32x2 i2 = __builtin_amdgcn_cvt_pk_f32_fp8((int)e2i[ii], false);
        const f32x2 i3 = __builtin_amdgcn_cvt_pk_f32_fp8((int)e3i[ii], false);
        const float bx = bfl(b0) + sdi * (i1.x + i2.x + i3.x);
        const float by = bfh(b0) + sdi * (i1.y + i2.y + i3.y);
        float d = ax * bx + ay * by;
        #pragma unroll
        for (int off = 32; off > 0; off >>= 1) d += __shfl_down(d, off);
        if (lane == 0) {
            d *= (1.f / 16.f);
            const float pred = 1.f / (1.f + expf(-d));
            if (p < 2 * BATCH) {
                const float ls  = logsigmoidf(d);
                const float lsn = logsigmoidf(-d);
                s_bce   += (p < BATCH) ? -ls : -lsn;
                s_pred  += pred;
                s_plogp += pred * ls;
            } else {
                s_ul += pred;
            }
        }
    }
    __shared__ float red[4][4];
    if (lane == 0) {
        red[wid][0] = s_bce; red[wid][1] = s_pred;
        red[wid][2] = s_plogp; red[wid][3] = s_ul;
    }
    __syncthreads();
    if (threadIdx.x < 4) {
        lossPart[blockIdx.x * 4 + threadIdx.x] =
            red[0][threadIdx.x] + red[1][threadIdx.x]
          + red[2][threadIdx.x] + red[3][threadIdx.x];
    }
}

// ---------------- finalize: reduce 512x4 partials, one block ------------------
__global__ void finalize_kernel(const float* __restrict__ lossPart,
                                float* __restrict__ out) {
    const int t = threadIdx.x;           // 256 threads
    const int lane = t & 63, wid = t >> 6;   // wave wid handles category wid
    float s = 0.f;
    for (int b = lane; b < LOSS_BLOCKS; b += 64)
        s += lossPart[b * 4 + wid];
    #pragma unroll
    for (int off = 32; off > 0; off >>= 1) s += __shfl_down(s, off);
    __shared__ float cat[4];
    if (lane == 0) cat[wid] = s;
    __syncthreads();
    if (t == 0) {
        const float n = 2.f * BATCH;
        const float bce        = cat[0] / n;
        const float pred_avg   = cat[1] / n;
        const float plogp_avg  = cat[2] / n;
        const float predul_avg = cat[3] / n;
        const float info = ALPHA * (-pred_avg * logf(predul_avg)
                                    - (1.f - pred_avg) * logf(1.f - predul_avg))
                         + GAMMA * plogp_avg;
        out[0] = bce;
        out[1] = info;
    }
}

extern "C" void kernel_launch(void* const* d_in, const int* in_sizes, int n_in,
                              void* d_out, int out_size, void* d_ws, size_t ws_size,
                              hipStream_t stream) {
    const float* user_emb      = (const float*)d_in[0];
    const float* item_emb      = (const float*)d_in[1];
    const int*   edge_user     = (const int*)d_in[3];
    const int*   edge_item     = (const int*)d_in[4];
    const int*   users         = (const int*)d_in[5];
    const int*   pos_items     = (const int*)d_in[6];
    const int*   neg_items     = (const int*)d_in[7];
    const int*   sampled_user  = (const int*)d_in[8];
    const int*   sampled_items = (const int*)d_in[9];
    float* out = (float*)d_out;

    const size_t ebu = (size_t)(N_USERS + 1) * EMBQ * sizeof(unsigned int); // 12.8 MB
    const size_t ebi = (size_t)(N_ITEMS + 1) * EMBQ * sizeof(unsigned int); //  5.1 MB
    char* ws = (char*)d_ws;
    size_t off = 0;
    unsigned int* e0u = (unsigned int*)(ws + off); off += ebu;
    unsigned int* e1u = (unsigned int*)(ws + off); off += ebu;
    unsigned int* e2u = (unsigned int*)(ws + off); off += ebu;
    unsigned int* e3u = (unsigned int*)(ws + off); off += ebu;
    unsigned int* e0i = (unsigned int*)(ws + off); off += ebi;
    unsigned int* e1i = (unsigned int*)(ws + off); off += ebi;
    unsigned int* e2i = (unsigned int*)(ws + off); off += ebi;
    unsigned int* e3i = (unsigned int*)(ws + off); off += ebi;
    unsigned int* x0b = (unsigned int*)(ws + off); off += (size_t)N_NODES * EMBH * 4;
    float* lossPart = (float*)(ws + off); off += (size_t)LOSS_BLOCKS * 4 * 4;
    int*   tk    = (int*)(ws + off); off += 256;
    int*   deg   = (int*)(ws + off); off += (size_t)N_NODES * 4;
    int*   rs_u  = (int*)(ws + off); off += (size_t)N_USERS * 4;
    int*   rs_i  = (int*)(ws + off); off += (size_t)N_ITEMS * 4;
    int*   rend_u = (int*)(ws + off); off += (size_t)N_USERS * 4;
    int*   rend_i = (int*)(ws + off); off += (size_t)N_ITEMS * 4;
    float* isq_u = (float*)(ws + off); off += (size_t)N_USERS * 4;
    float* isq_i = (float*)(ws + off); off += (size_t)N_ITEMS * 4;
    unsigned short* csr_u = (unsigned short*)(ws + off); off += (size_t)CSRU_MAX * 2 + 256;
    int*   csr_i = (int*)(ws + off); off += (size_t)CSRI_MAX * 4;
    unsigned int* part_u = (unsigned int*)(ws + off); off += (size_t)N_EDGES * 4;
    unsigned int* part_i = (unsigned int*)(ws + off); off += (size_t)N_EDGES * 4;
    int*   histA   = (int*)(ws + off); off += (size_t)PART_BLOCKS * NB_T * 4;
    int*   woff    = (int*)(ws + off); off += (size_t)PART_BLOCKS * NB_T * 4;
    int*   bktCnt  = (int*)(ws + off); off += (size_t)NB_T * 4;
    int*   bktBase = (int*)(ws + off); off += (size_t)NB_T * 4;

    bucketA<<<PART_BLOCKS, 256, 0, stream>>>(edge_user, edge_item, histA, tk);
    bucketB1<<<NB_T, 256, 0, stream>>>(histA, woff, bktCnt, bktBase, tk);
    bucketC<<<PART_BLOCKS, 256, 0, stream>>>(edge_user, edge_item, woff,
                                             part_u, part_i);
    csr_build<<<NB_T, 256, 0, stream>>>(part_u, part_i, bktBase, bktCnt, tk,
                                        deg, isq_u, isq_i, rs_u, rs_i,
                                        rend_u, rend_i, csr_u, csr_i);
    init_kernel<<<4096, 256, 0, stream>>>(user_emb, item_emb, isq_u, isq_i,
                                          e0u, e0i, e1u, e2u, e3u, e1i, e2i, e3i,
                                          x0b);

    spmm_fused<<<UBLK8 + IBLK8, 256, 0, stream>>>(e0u, e0i, e1u, e1i, rs_u, rs_i,
                                                  rend_u, rend_i, csr_u, csr_i,
                                                  isq_u, isq_i);
    spmm_fused<<<UBLK8 + IBLK8, 256, 0, stream>>>(e1u, e1i, e2u, e2i, rs_u, rs_i,
                                                  rend_u, rend_i, csr_u, csr_i,
                                                  isq_u, isq_i);
    spmm_fused<<<UBLK8 + IBLK8, 256, 0, stream>>>(e2u, e2i, e3u, e3i, rs_u, rs_i,
                                                  rend_u, rend_i, csr_u, csr_i,
                                                  isq_u, isq_i);

    loss_kernel<<<LOSS_BLOCKS, 256, 0, stream>>>(x0b,
                                         (const unsigned short*)e1u,
                                         (const unsigned short*)e2u,
                                         (const unsigned short*)e3u,
                                         (const unsigned short*)e1i,
                                         (const unsigned short*)e2i,
                                         (const unsigned short*)e3i,
                                         deg, users, pos_items, neg_items,
                                         sampled_user, sampled_items, lossPart);
    finalize_kernel<<<1, 256, 0, stream>>>(lossPart, out);
}

// Round 22
// 217.226 us; speedup vs baseline: 1.0942x; 1.0433x over previous
//
#include <hip/hip_runtime.h>
#include <math.h>

#define N_USERS 100000
#define N_ITEMS 40000
#define N_NODES (N_USERS + N_ITEMS)
#define EMB 128
#define EMBQ (EMB / 4)            /* 32 uints of packed 4x fp8 per row */
#define BATCH 8192
#define N_EDGES 1000000
#define ALPHA 0.1f
#define GAMMA 0.01f
#define FP8_SCALE 32.0f
#define INV_FP8_SCALE (1.0f / FP8_SCALE)

/* ---- bucket-sort CSR build geometry ---- */
#define RB_U 512                                /* rows per user bucket (shift 9) */
#define NB_U ((N_USERS + RB_U - 1) / RB_U)      /* 196 */
#define RB_I 256                                /* rows per item bucket (shift 8) */
#define NB_I ((N_ITEMS + RB_I - 1) / RB_I)      /* 157 */
#define NB_T (NB_U + NB_I)                      /* 353 */
#define PART_BLOCKS 256

#define CSRU_MAX (N_EDGES + 4 * (NB_U * RB_U))  /* u16 entries */
#define CSRI_MAX (N_EDGES + 4 * (NB_I * RB_I))  /* u32 entries */

#define UBLK8 ((N_USERS + 7) / 8)               /* 12500: 8 rows per block */
#define IBLK8 ((N_ITEMS + 7) / 8)               /* 5000 */

#define LOSS_BLOCKS 512

typedef float f32x2 __attribute__((ext_vector_type(2)));

__device__ inline float bfl(unsigned int w) { return __uint_as_float(w << 16); }
__device__ inline float bfh(unsigned int w) { return __uint_as_float(w & 0xFFFF0000u); }

// ---------- fp8x4 dot-accumulate helper --------------------------------------
__device__ inline void acc4(unsigned int v, float& s0, float& s1, float& s2, float& s3) {
    const f32x2 lo = __builtin_amdgcn_cvt_pk_f32_fp8((int)v, false);
    const f32x2 hi = __builtin_amdgcn_cvt_pk_f32_fp8((int)v, true);
    s0 += lo.x; s1 += lo.y; s2 += hi.x; s3 += hi.y;
}

// ============ CSR build (bucket sort + ticket allocation, no scans) ===========
// tickets: tk[0]=part_u, tk[1]=part_i, tk[2]=csr_u, tk[3]=csr_i

// ---- A: per-block bucket histograms; block 0 zeroes tickets -------------------
__global__ void bucketA(const int* __restrict__ eu, const int* __restrict__ ev,
                        int* __restrict__ histA /* [PART_BLOCKS][NB_T] */,
                        int* __restrict__ tk) {
    if (blockIdx.x == 0 && threadIdx.x < 4) tk[threadIdx.x] = 0;
    __shared__ int h[NB_T];
    for (int k = threadIdx.x; k < NB_T; k += 256) h[k] = 0;
    __syncthreads();
    const int b = blockIdx.x;
    const int beg = (int)((long long)N_EDGES * b / PART_BLOCKS);
    const int end = (int)((long long)N_EDGES * (b + 1) / PART_BLOCKS);
    for (int i = beg + threadIdx.x; i < end; i += 256) {
        const int u = __builtin_nontemporal_load(&eu[i]);
        const int v = __builtin_nontemporal_load(&ev[i]);
        atomicAdd(&h[u >> 9], 1);
        atomicAdd(&h[NB_U + (v >> 8)], 1);
    }
    __syncthreads();
    for (int k = threadIdx.x; k < NB_T; k += 256) histA[b * NB_T + k] = h[k];
}

// ---- B1: per-bucket scan over block counts + TICKET part-region claim --------
__global__ void bucketB1(const int* __restrict__ histA, int* __restrict__ woff,
                         int* __restrict__ bktCnt, int* __restrict__ bktBase,
                         int* __restrict__ tk) {
    const int k = blockIdx.x;            // bucket id
    const int t = threadIdx.x;           // block id b = t (256 threads)
    const int lane = t & 63, wid = t >> 6;
    const int v = histA[t * NB_T + k];
    int x = v;
    #pragma unroll
    for (int off = 1; off < 64; off <<= 1) {
        const int y = __shfl_up(x, off);
        if (lane >= off) x += y;
    }
    __shared__ int wt[4];
    __shared__ int base;
    if (lane == 63) wt[wid] = x;
    __syncthreads();
    int wo = 0;
    for (int q = 0; q < wid; ++q) wo += wt[q];
    if (t == 255) {
        const int tot = wo + x;
        bktCnt[k] = tot;
        const int b0 = atomicAdd(&tk[(k < NB_U) ? 0 : 1], tot);  // claim region
        base = b0;
        bktBase[k] = b0;
    }
    __syncthreads();
    woff[t * NB_T + k] = base + wo + x - v;   // absolute exclusive offset
}

// ---- C: partition edges into bucket-contiguous arrays (packed u32) -----------
// pack user-part:  lrow(9b) | v<<9   pack item-part:  lrow(8b) | u<<8
__global__ void bucketC(const int* __restrict__ eu, const int* __restrict__ ev,
                        const int* __restrict__ woff,
                        unsigned int* __restrict__ part_u,
                        unsigned int* __restrict__ part_i) {
    __shared__ int cur[NB_T];
    const int b = blockIdx.x;
    for (int k = threadIdx.x; k < NB_T; k += 256)
        cur[k] = woff[b * NB_T + k];
    __syncthreads();
    const int beg = (int)((long long)N_EDGES * b / PART_BLOCKS);
    const int end = (int)((long long)N_EDGES * (b + 1) / PART_BLOCKS);
    for (int i = beg + threadIdx.x; i < end; i += 256) {
        const int u = __builtin_nontemporal_load(&eu[i]);
        const int v = __builtin_nontemporal_load(&ev[i]);
        const int pu = atomicAdd(&cur[u >> 9], 1);
        part_u[pu] = (unsigned int)((u & (RB_U - 1)) | (v << 9));
        const int pi = atomicAdd(&cur[NB_U + (v >> 8)], 1);
        part_i[pi] = (unsigned int)((v & (RB_I - 1)) | (u << 8));
    }
}

// ---- csr_build: histogram + prefix + TICKET csr claim + pad + rank-scatter ---
__global__ void csr_build(const unsigned int* __restrict__ part_u,
                          const unsigned int* __restrict__ part_i,
                          const int* __restrict__ bktBase, const int* __restrict__ bktCnt,
                          int* __restrict__ tk,
                          int* __restrict__ deg, float* __restrict__ isq_u,
                          float* __restrict__ isq_i,
                          int* __restrict__ rs_u, int* __restrict__ rs_i,
                          int* __restrict__ rend_u, int* __restrict__ rend_i,
                          unsigned short* __restrict__ csr_u, int* __restrict__ csr_i) {
    const int k = blockIdx.x;
    const bool isU = (k < NB_U);
    const int R = isU ? RB_U : RB_I;
    const int row0 = isU ? k * RB_U : (k - NB_U) * RB_I;
    const int Nside = isU ? N_USERS : N_ITEMS;
    const unsigned int* part = isU ? part_u : part_i;
    const int mask = R - 1;
    const int shift = isU ? 9 : 8;
    __shared__ int dh[RB_U];
    __shared__ int cur[RB_U];
    __shared__ int cbase;
    for (int r = threadIdx.x; r < R; r += 256) dh[r] = 0;
    __syncthreads();
    const int base = bktBase[k], cnt = bktCnt[k];
    for (int j = threadIdx.x; j < cnt; j += 256)
        atomicAdd(&dh[part[base + j] & mask], 1);
    __syncthreads();
    const int t = threadIdx.x, lane = t & 63, wid = t >> 6;
    const int r0 = 2 * t, r1 = 2 * t + 1;
    const int d0 = (r0 < R) ? dh[r0] : 0;
    const int d1 = (r1 < R) ? dh[r1] : 0;
    const int v0 = (d0 + 3) & ~3, v1 = (d1 + 3) & ~3;   // pad to 4
    const int s = v0 + v1;
    int x = s;
    #pragma unroll
    for (int off = 1; off < 64; off <<= 1) {
        const int y = __shfl_up(x, off);
        if (lane >= off) x += y;
    }
    __shared__ int wtot[4];
    if (lane == 63) wtot[wid] = x;
    __syncthreads();
    int wo = 0;
    for (int q = 0; q < wid; ++q) wo += wtot[q];
    const int pref = wo + x - s;              // exclusive padded prefix in block
    if (t == 255) {
        cbase = atomicAdd(&tk[isU ? 2 : 3], wo + x);   // claim csr region
    }
    __syncthreads();
    const int cb = cbase;
    if (r0 < R && row0 + r0 < Nside) {
        const int st = cb + pref;
        deg[(isU ? 0 : N_USERS) + row0 + r0] = d0;
        cur[r0] = st;
        if (isU) { isq_u[row0 + r0] = (d0 > 0) ? (1.0f / sqrtf((float)d0)) : 0.f;
                   rs_u[row0 + r0] = st; rend_u[row0 + r0] = st + v0;
                   for (int q = d0; q < v0; ++q) csr_u[st + q] = (unsigned short)N_ITEMS; }
        else     { isq_i[row0 + r0] = (d0 > 0) ? (1.0f / sqrtf((float)d0)) : 0.f;
                   rs_i[row0 + r0] = st; rend_i[row0 + r0] = st + v0;
                   for (int q = d0; q < v0; ++q) csr_i[st + q] = N_USERS; }
    } else if (r0 < R) cur[r0] = 0;
    if (r1 < R && row0 + r1 < Nside) {
        const int st = cb + pref + v0;
        deg[(isU ? 0 : N_USERS) + row0 + r1] = d1;
        cur[r1] = st;
        if (isU) { isq_u[row0 + r1] = (d1 > 0) ? (1.0f / sqrtf((float)d1)) : 0.f;
                   rs_u[row0 + r1] = st; rend_u[row0 + r1] = st + v1;
                   for (int q = d1; q < v1; ++q) csr_u[st + q] = (unsigned short)N_ITEMS; }
        else     { isq_i[row0 + r1] = (d1 > 0) ? (1.0f / sqrtf((float)d1)) : 0.f;
                   rs_i[row0 + r1] = st; rend_i[row0 + r1] = st + v1;
                   for (int q = d1; q < v1; ++q) csr_i[st + q] = N_USERS; }
    } else if (r1 < R) cur[r1] = 0;
    __syncthreads();
    for (int j = threadIdx.x; j < cnt; j += 256) {
        const unsigned int e = part[base + j];
        const int pos = atomicAdd(&cur[e & mask], 1);
        const int col = (int)(e >> shift);
        if (isU) csr_u[pos] = (unsigned short)col; else csr_i[pos] = col;
    }
}

// ================== embedding pipeline ========================================

// -------- init: e0{u,i} = fp8(S*isq*x0); +zero dummy rows ---------------------
__global__ void init_kernel(const float* __restrict__ user_emb,
                            const float* __restrict__ item_emb,
                            const float* __restrict__ isq_u,
                            const float* __restrict__ isq_i,
                            unsigned int* __restrict__ e0u,
                            unsigned int* __restrict__ e0i,
                            unsigned int* __restrict__ e1u,
                            unsigned int* __restrict__ e2u,
                            unsigned int* __restrict__ e3u,
                            unsigned int* __restrict__ e1i,
                            unsigned int* __restrict__ e2i,
                            unsigned int* __restrict__ e3i) {
    if (blockIdx.x == 0 && threadIdx.x < 256) {
        const int t = threadIdx.x;   // 8 buffers x 32 words
        unsigned int* bufs[8] = {e0u, e1u, e2u, e3u, e0i, e1i, e2i, e3i};
        const int b = t >> 5;
        const size_t row = (b < 4) ? (size_t)N_USERS : (size_t)N_ITEMS;
        bufs[b][row * EMBQ + (t & 31)] = 0u;
    }
    const int total = N_NODES * EMBQ;
    const int utotal = N_USERS * EMBQ;
    int i = blockIdx.x * blockDim.x + threadIdx.x;
    const int stride = gridDim.x * blockDim.x;
    for (; i < total; i += stride) {
        const int node = i >> 5;
        const int q    = i & 31;
        float4 v; float n;
        if (node < N_USERS) {
            v = ((const float4*)(user_emb + (size_t)node * EMB))[q];
            n = FP8_SCALE * isq_u[node];
        } else {
            v = ((const float4*)(item_emb + (size_t)(node - N_USERS) * EMB))[q];
            n = FP8_SCALE * isq_i[node - N_USERS];
        }
        int pk = __builtin_amdgcn_cvt_pk_fp8_f32(n * v.x, n * v.y, 0, false);
        pk = __builtin_amdgcn_cvt_pk_fp8_f32(n * v.z, n * v.w, pk, true);
        if (node < N_USERS) e0u[i] = (unsigned int)pk;
        else                e0i[i - utotal] = (unsigned int)pk;
    }
}

// ---- fused per-layer SpMM: ITEM blocks first, 16-deep item MLP ---------------
__global__ void spmm_fused(const unsigned int* __restrict__ cur_u,
                           const unsigned int* __restrict__ cur_i,
                           unsigned int* __restrict__ nxt_u,
                           unsigned int* __restrict__ nxt_i,
                           const int* __restrict__ rs_u,
                           const int* __restrict__ rs_i,
                           const int* __restrict__ rend_u,
                           const int* __restrict__ rend_i,
                           const unsigned short* __restrict__ csr_u,
                           const int* __restrict__ csr_i,
                           const float* __restrict__ isq_u,
                           const float* __restrict__ isq_i) {
    const int lane = threadIdx.x & 63;
    const int half = lane >> 5;
    const int sub  = lane & 31;
    const int b = blockIdx.x;
    const int hw = (threadIdx.x >> 6) * 2 + half;    // half-wave id 0..7
    float s0 = 0.f, s1 = 0.f, s2 = 0.f, s3 = 0.f;
    if (b < IBLK8) {                                 // ---- item rows ----
        const int w = b * 8 + hw;
        if (w >= N_ITEMS) return;
        const int beg = rs_i[w];
        const int end = rend_i[w];
        int j = beg;
        for (; j + 16 <= end; j += 16) {             // 16 gathers in flight
            const int4 ca = *(const int4*)(csr_i + j);
            const int4 cb = *(const int4*)(csr_i + j + 4);
            const int4 cc = *(const int4*)(csr_i + j + 8);
            const int4 cd = *(const int4*)(csr_i + j + 12);
            const unsigned int v0 = cur_u[(size_t)ca.x * EMBQ + sub];
            const unsigned int v1 = cur_u[(size_t)ca.y * EMBQ + sub];
            const unsigned int v2 = cur_u[(size_t)ca.z * EMBQ + sub];
            const unsigned int v3 = cur_u[(size_t)ca.w * EMBQ + sub];
            const unsigned int v4 = cur_u[(size_t)cb.x * EMBQ + sub];
            const unsigned int v5 = cur_u[(size_t)cb.y * EMBQ + sub];
            const unsigned int v6 = cur_u[(size_t)cb.z * EMBQ + sub];
            const unsigned int v7 = cur_u[(size_t)cb.w * EMBQ + sub];
            const unsigned int v8 = cur_u[(size_t)cc.x * EMBQ + sub];
            const unsigned int v9 = cur_u[(size_t)cc.y * EMBQ + sub];
            const unsigned int va = cur_u[(size_t)cc.z * EMBQ + sub];
            const unsigned int vb = cur_u[(size_t)cc.w * EMBQ + sub];
            const unsigned int vc = cur_u[(size_t)cd.x * EMBQ + sub];
            const unsigned int vd = cur_u[(size_t)cd.y * EMBQ + sub];
            const unsigned int ve = cur_u[(size_t)cd.z * EMBQ + sub];
            const unsigned int vf = cur_u[(size_t)cd.w * EMBQ + sub];
            acc4(v0, s0, s1, s2, s3); acc4(v1, s0, s1, s2, s3);
            acc4(v2, s0, s1, s2, s3); acc4(v3, s0, s1, s2, s3);
            acc4(v4, s0, s1, s2, s3); acc4(v5, s0, s1, s2, s3);
            acc4(v6, s0, s1, s2, s3); acc4(v7, s0, s1, s2, s3);
            acc4(v8, s0, s1, s2, s3); acc4(v9, s0, s1, s2, s3);
            acc4(va, s0, s1, s2, s3); acc4(vb, s0, s1, s2, s3);
            acc4(vc, s0, s1, s2, s3); acc4(vd, s0, s1, s2, s3);
            acc4(ve, s0, s1, s2, s3); acc4(vf, s0, s1, s2, s3);
        }
        for (; j + 8 <= end; j += 8) {
            const int4 ca = *(const int4*)(csr_i + j);
            const int4 cb = *(const int4*)(csr_i + j + 4);
            const unsigned int v0 = cur_u[(size_t)ca.x * EMBQ + sub];
            const unsigned int v1 = cur_u[(size_t)ca.y * EMBQ + sub];
            const unsigned int v2 = cur_u[(size_t)ca.z * EMBQ + sub];
            const unsigned int v3 = cur_u[(size_t)ca.w * EMBQ + sub];
            const unsigned int v4 = cur_u[(size_t)cb.x * EMBQ + sub];
            const unsigned int v5 = cur_u[(size_t)cb.y * EMBQ + sub];
            const unsigned int v6 = cur_u[(size_t)cb.z * EMBQ + sub];
            const unsigned int v7 = cur_u[(size_t)cb.w * EMBQ + sub];
            acc4(v0, s0, s1, s2, s3); acc4(v1, s0, s1, s2, s3);
            acc4(v2, s0, s1, s2, s3); acc4(v3, s0, s1, s2, s3);
            acc4(v4, s0, s1, s2, s3); acc4(v5, s0, s1, s2, s3);
            acc4(v6, s0, s1, s2, s3); acc4(v7, s0, s1, s2, s3);
        }
        if (j < end) {
            const int4 cc = *(const int4*)(csr_i + j);
            const unsigned int v0 = cur_u[(size_t)cc.x * EMBQ + sub];
            const unsigned int v1 = cur_u[(size_t)cc.y * EMBQ + sub];
            const unsigned int v2 = cur_u[(size_t)cc.z * EMBQ + sub];
            const unsigned int v3 = cur_u[(size_t)cc.w * EMBQ + sub];
            acc4(v0, s0, s1, s2, s3); acc4(v1, s0, s1, s2, s3);
            acc4(v2, s0, s1, s2, s3); acc4(v3, s0, s1, s2, s3);
        }
        const float n = isq_i[w];
        const float sc = n * n;
        int pk = __builtin_amdgcn_cvt_pk_fp8_f32(sc * s0, sc * s1, 0, false);
        pk = __builtin_amdgcn_cvt_pk_fp8_f32(sc * s2, sc * s3, pk, true);
        nxt_i[(size_t)w * EMBQ + sub] = (unsigned int)pk;
    } else {                                         // ---- user rows ----
        const int w = (b - IBLK8) * 8 + hw;
        if (w >= N_USERS) return;
        const int beg = rs_u[w];
        const int end = rend_u[w];
        int j = beg;
        for (; j + 8 <= end; j += 8) {
            const ushort4 ca = *(const ushort4*)(csr_u + j);
            const ushort4 cb = *(const ushort4*)(csr_u + j + 4);
            const unsigned int v0 = cur_i[(size_t)ca.x * EMBQ + sub];
            const unsigned int v1 = cur_i[(size_t)ca.y * EMBQ + sub];
            const unsigned int v2 = cur_i[(size_t)ca.z * EMBQ + sub];
            const unsigned int v3 = cur_i[(size_t)ca.w * EMBQ + sub];
            const unsigned int v4 = cur_i[(size_t)cb.x * EMBQ + sub];
            const unsigned int v5 = cur_i[(size_t)cb.y * EMBQ + sub];
            const unsigned int v6 = cur_i[(size_t)cb.z * EMBQ + sub];
            const unsigned int v7 = cur_i[(size_t)cb.w * EMBQ + sub];
            acc4(v0, s0, s1, s2, s3); acc4(v1, s0, s1, s2, s3);
            acc4(v2, s0, s1, s2, s3); acc4(v3, s0, s1, s2, s3);
            acc4(v4, s0, s1, s2, s3); acc4(v5, s0, s1, s2, s3);
            acc4(v6, s0, s1, s2, s3); acc4(v7, s0, s1, s2, s3);
        }
        if (j < end) {
            const ushort4 cc = *(const ushort4*)(csr_u + j);
            const unsigned int v0 = cur_i[(size_t)cc.x * EMBQ + sub];
            const unsigned int v1 = cur_i[(size_t)cc.y * EMBQ + sub];
            const unsigned int v2 = cur_i[(size_t)cc.z * EMBQ + sub];
            const unsigned int v3 = cur_i[(size_t)cc.w * EMBQ + sub];
            acc4(v0, s0, s1, s2, s3); acc4(v1, s0, s1, s2, s3);
            acc4(v2, s0, s1, s2, s3); acc4(v3, s0, s1, s2, s3);
        }
        const float n = isq_u[w];
        const float sc = n * n;
        int pk = __builtin_amdgcn_cvt_pk_fp8_f32(sc * s0, sc * s1, 0, false);
        pk = __builtin_amdgcn_cvt_pk_fp8_f32(sc * s2, sc * s3, pk, true);
        nxt_u[(size_t)w * EMBQ + sub] = (unsigned int)pk;
    }
}

__device__ inline float logsigmoidf(float x) {
    return (x >= 0.f) ? -log1pf(expf(-x)) : (x - log1pf(expf(x)));
}

// ---------------- fused losses: per-block partials, NO atomics ----------------
// acc-row on the fly: x0 (fp32 originals) + sqrt(deg)/S * (w1+w2+w3 fp8).
__global__ void loss_kernel(const float* __restrict__ user_emb,
                            const float* __restrict__ item_emb,
                            const unsigned short* __restrict__ e1u,
                            const unsigned short* __restrict__ e2u,
                            const unsigned short* __restrict__ e3u,
                            const unsigned short* __restrict__ e1i,
                            const unsigned short* __restrict__ e2i,
                            const unsigned short* __restrict__ e3i,
                            const int* __restrict__ deg,
                            const int* __restrict__ users,
                            const int* __restrict__ pos_items,
                            const int* __restrict__ neg_items,
                            const int* __restrict__ sampled_user,
                            const int* __restrict__ sampled_items,
                            float* __restrict__ lossPart) {
    const int lane = threadIdx.x & 63;
    const int wid  = threadIdx.x >> 6;
    const int gw   = blockIdx.x * 4 + wid;
    const int nw   = gridDim.x * 4;
    float s_bce = 0.f, s_pred = 0.f, s_plogp = 0.f, s_ul = 0.f;
    for (int p = gw; p < 4 * BATCH; p += nw) {
        int u, it;
        if (p < 2 * BATCH) {
            if (p < BATCH) { u = users[p];          it = pos_items[p]; }
            else           { u = users[p - BATCH];  it = neg_items[p - BATCH]; }
        } else {
            const int q = p - 2 * BATCH;
            u = sampled_user[q]; it = sampled_items[q];
        }
        const float sdu = sqrtf((float)deg[u]) * INV_FP8_SCALE;
        const float2 a0 = ((const float2*)(user_emb + (size_t)u * EMB))[lane];
        const size_t ui = (size_t)u * 64 + lane;
        const f32x2 u1 = __builtin_amdgcn_cvt_pk_f32_fp8((int)e1u[ui], false);
        const f32x2 u2 = __builtin_amdgcn_cvt_pk_f32_fp8((int)e2u[ui], false);
        const f32x2 u3 = __builtin_amdgcn_cvt_pk_f32_fp8((int)e3u[ui], false);
        const float ax = a0.x + sdu * (u1.x + u2.x + u3.x);
        const float ay = a0.y + sdu * (u1.y + u2.y + u3.y);
        const float sdi = sqrtf((float)deg[N_USERS + it]) * INV_FP8_SCALE;
        const float2 b0 = ((const float2*)(item_emb + (size_t)it * EMB))[lane];
        const size_t ii = (size_t)it * 64 + lane;
        const f32x2 i1 = __builtin_amdgcn_cvt_pk_f32_fp8((int)e1i[ii], false);
        const f32x2 i2 = __builtin_amdgcn_cvt_pk_f32_fp8((int)e2i[ii], false);
        const f32x2 i3 = __builtin_amdgcn_cvt_pk_f32_fp8((int)e3i[ii], false);
        const float bx = b0.x + sdi * (i1.x + i2.x + i3.x);
        const float by = b0.y + sdi * (i1.y + i2.y + i3.y);
        float d = ax * bx + ay * by;
        #pragma unroll
        for (int off = 32; off > 0; off >>= 1) d += __shfl_down(d, off);
        if (lane == 0) {
            d *= (1.f / 16.f);
            const float pred = 1.f / (1.f + expf(-d));
            if (p < 2 * BATCH) {
                const float ls  = logsigmoidf(d);
                const float lsn = logsigmoidf(-d);
                s_bce   += (p < BATCH) ? -ls : -lsn;
                s_pred  += pred;
                s_plogp += pred * ls;
            } else {
                s_ul += pred;
            }
        }
    }
    __shared__ float red[4][4];
    if (lane == 0) {
        red[wid][0] = s_bce; red[wid][1] = s_pred;
        red[wid][2] = s_plogp; red[wid][3] = s_ul;
    }
    __syncthreads();
    if (threadIdx.x < 4) {
        lossPart[blockIdx.x * 4 + threadIdx.x] =
            red[0][threadIdx.x] + red[1][threadIdx.x]
          + red[2][threadIdx.x] + red[3][threadIdx.x];
    }
}

// ---------------- finalize: reduce 512x4 partials, one block ------------------
__global__ void finalize_kernel(const float* __restrict__ lossPart,
                                float* __restrict__ out) {
    const int t = threadIdx.x;           // 256 threads
    const int lane = t & 63, wid = t >> 6;   // wave wid handles category wid
    float s = 0.f;
    for (int b = lane; b < LOSS_BLOCKS; b += 64)
        s += lossPart[b * 4 + wid];
    #pragma unroll
    for (int off = 32; off > 0; off >>= 1) s += __shfl_down(s, off);
    __shared__ float cat[4];
    if (lane == 0) cat[wid] = s;
    __syncthreads();
    if (t == 0) {
        const float n = 2.f * BATCH;
        const float bce        = cat[0] / n;
        const float pred_avg   = cat[1] / n;
        const float plogp_avg  = cat[2] / n;
        const float predul_avg = cat[3] / n;
        const float info = ALPHA * (-pred_avg * logf(predul_avg)
                                    - (1.f - pred_avg) * logf(1.f - predul_avg))
                         + GAMMA * plogp_avg;
        out[0] = bce;
        out[1] = info;
    }
}

extern "C" void kernel_launch(void* const* d_in, const int* in_sizes, int n_in,
                              void* d_out, int out_size, void* d_ws, size_t ws_size,
                              hipStream_t stream) {
    const float* user_emb      = (const float*)d_in[0];
    const float* item_emb      = (const float*)d_in[1];
    const int*   edge_user     = (const int*)d_in[3];
    const int*   edge_item     = (const int*)d_in[4];
    const int*   users         = (const int*)d_in[5];
    const int*   pos_items     = (const int*)d_in[6];
    const int*   neg_items     = (const int*)d_in[7];
    const int*   sampled_user  = (const int*)d_in[8];
    const int*   sampled_items = (const int*)d_in[9];
    float* out = (float*)d_out;

    const size_t ebu = (size_t)(N_USERS + 1) * EMBQ * sizeof(unsigned int); // 12.8 MB
    const size_t ebi = (size_t)(N_ITEMS + 1) * EMBQ * sizeof(unsigned int); //  5.1 MB
    char* ws = (char*)d_ws;
    size_t off = 0;
    unsigned int* e0u = (unsigned int*)(ws + off); off += ebu;
    unsigned int* e1u = (unsigned int*)(ws + off); off += ebu;
    unsigned int* e2u = (unsigned int*)(ws + off); off += ebu;
    unsigned int* e3u = (unsigned int*)(ws + off); off += ebu;
    unsigned int* e0i = (unsigned int*)(ws + off); off += ebi;
    unsigned int* e1i = (unsigned int*)(ws + off); off += ebi;
    unsigned int* e2i = (unsigned int*)(ws + off); off += ebi;
    unsigned int* e3i = (unsigned int*)(ws + off); off += ebi;
    float* lossPart = (float*)(ws + off); off += (size_t)LOSS_BLOCKS * 4 * 4;
    int*   tk    = (int*)(ws + off); off += 256;
    int*   deg   = (int*)(ws + off); off += (size_t)N_NODES * 4;
    int*   rs_u  = (int*)(ws + off); off += (size_t)N_USERS * 4;
    int*   rs_i  = (int*)(ws + off); off += (size_t)N_ITEMS * 4;
    int*   rend_u = (int*)(ws + off); off += (size_t)N_USERS * 4;
    int*   rend_i = (int*)(ws + off); off += (size_t)N_ITEMS * 4;
    float* isq_u = (float*)(ws + off); off += (size_t)N_USERS * 4;
    float* isq_i = (float*)(ws + off); off += (size_t)N_ITEMS * 4;
    unsigned short* csr_u = (unsigned short*)(ws + off); off += (size_t)CSRU_MAX * 2 + 256;
    int*   csr_i = (int*)(ws + off); off += (size_t)CSRI_MAX * 4;
    unsigned int* part_u = (unsigned int*)(ws + off); off += (size_t)N_EDGES * 4;
    unsigned int* part_i = (unsigned int*)(ws + off); off += (size_t)N_EDGES * 4;
    int*   histA   = (int*)(ws + off); off += (size_t)PART_BLOCKS * NB_T * 4;
    int*   woff    = (int*)(ws + off); off += (size_t)PART_BLOCKS * NB_T * 4;
    int*   bktCnt  = (int*)(ws + off); off += (size_t)NB_T * 4;
    int*   bktBase = (int*)(ws + off); off += (size_t)NB_T * 4;

    bucketA<<<PART_BLOCKS, 256, 0, stream>>>(edge_user, edge_item, histA, tk);
    bucketB1<<<NB_T, 256, 0, stream>>>(histA, woff, bktCnt, bktBase, tk);
    bucketC<<<PART_BLOCKS, 256, 0, stream>>>(edge_user, edge_item, woff,
                                             part_u, part_i);
    csr_build<<<NB_T, 256, 0, stream>>>(part_u, part_i, bktBase, bktCnt, tk,
                                        deg, isq_u, isq_i, rs_u, rs_i,
                                        rend_u, rend_i, csr_u, csr_i);
    init_kernel<<<4096, 256, 0, stream>>>(user_emb, item_emb, isq_u, isq_i,
                                          e0u, e0i, e1u, e2u, e3u, e1i, e2i, e3i);

    spmm_fused<<<UBLK8 + IBLK8, 256, 0, stream>>>(e0u, e0i, e1u, e1i, rs_u, rs_i,
                                                  rend_u, rend_i, csr_u, csr_i,
                                                  isq_u, isq_i);
    spmm_fused<<<UBLK8 + IBLK8, 256, 0, stream>>>(e1u, e1i, e2u, e2i, rs_u, rs_i,
                                                  rend_u, rend_i, csr_u, csr_i,
                                                  isq_u, isq_i);
    spmm_fused<<<UBLK8 + IBLK8, 256, 0, stream>>>(e2u, e2i, e3u, e3i, rs_u, rs_i,
                                                  rend_u, rend_i, csr_u, csr_i,
                                                  isq_u, isq_i);

    loss_kernel<<<LOSS_BLOCKS, 256, 0, stream>>>(user_emb, item_emb,
                                         (const unsigned short*)e1u,
                                         (const unsigned short*)e2u,
                                         (const unsigned short*)e3u,
                                         (const unsigned short*)e1i,
                                         (const unsigned short*)e2i,
                                         (const unsigned short*)e3i,
                                         deg, users, pos_items, neg_items,
                                         sampled_user, sampled_items, lossPart);
    finalize_kernel<<<1, 256, 0, stream>>>(lossPart, out);
}